// Round 6
// baseline (972.812 us; speedup 1.0000x reference)
//
#include <hip/hip_runtime.h>
#include <hip/hip_bf16.h>

// TFSwinSelfAttention fused kernel for MI355X (gfx950).
// Shapes: B=4096 windows, N=49 tokens, D=256 = 8 heads x 32.
// fp32 in/out; internal bf16 MFMA compute (fp32 accum) within harness tol.
//
// Round-8 (release BOTH occupancy constraints):
//   Round-7 result: Occ stuck at 11.7% (1 block/CU) despite LDS 81,920
//   allowing "exactly 2" blocks (2x81,920 = 163,840 = exactly 160 KiB) and
//   VGPR=228 arch. Either the LDS allocator can't exact-fit (granule
//   rounding), or arch+AGPR unified total > 256 -> 1 wave/SIMD. Can't
//   distinguish; release both:
//   1. LDS 81,920 -> 76,944 B (>=7 KB slack): mask dropped from LDS, read
//      from GLOBAL fp32 in softmax (reads are coalesced: c=16nt+cc -> 16
//      consecutive floats; 9.6 KB/window slice is L1-resident, reused 8x).
//      Scattered tab gather stays in LDS.
//   2. Registers: stream the head tail per 16-row block (mt). Round-7 held
//      s[4][4](64) + o[4][2](32) + linv(16) live across the head. Now:
//      preload aq[4]/bkf[4]/bvf[4] (48 regs; ALSO required for the P-over-
//      q/k overlay to stay legal in streamed order), then per mt:
//      4 score MFMAs (s=16) -> softmax (4 rows) -> P writes -> 4 PV MFMAs
//      (o=8) -> normalize+store. Peak live ~-90 regs, shorter dep chains.
//   Watch: Occ ~12 again with small VGPR + 77KB LDS => non-{LDS,VGPR} limit.
//
// Carried: P[64][64] overlays q+k (q/k fully in regs before first P write);
// single block barrier; end-of-head lgkmcnt fence for the WAR hazard.

typedef __bf16 bf16;
typedef __attribute__((ext_vector_type(8))) __bf16 bf16x8;
typedef __attribute__((ext_vector_type(4))) float f32x4;

__device__ __forceinline__ f32x4 mfma16(bf16x8 a, bf16x8 b, f32x4 c) {
    return __builtin_amdgcn_mfma_f32_16x16x32_bf16(a, b, c, 0, 0, 0);
}

// --------------------------------------------------------------------------
// Kernel 0: repack fp32 weights into bf16 B-fragment order (unchanged).
// packed[((t*16 + nt)*8 + kk)*512 + L*8 + j] = W_t[kk*32 + (L>>4)*8 + j][nt*16 + (L&15)]
__global__ void repack_w(const float* __restrict__ wq, const float* __restrict__ wk,
                         const float* __restrict__ wv, bf16* __restrict__ pk) {
    int i = blockIdx.x * 256 + threadIdx.x;      // 0 .. 3*65536-1
    int t = i >> 16;
    int r = i & 65535;
    int kr = r >> 8, nc = r & 255;
    const float* w = (t == 0) ? wq : (t == 1) ? wk : wv;
    int nt = nc >> 4;
    int kk = kr >> 5;
    int Ln = (((kr >> 3) & 3) << 4) | (nc & 15);
    int j  = kr & 7;
    pk[(((t * 16 + nt) * 8 + kk) << 9) + Ln * 8 + j] = (bf16)w[r];
}

// --------------------------------------------------------------------------
#define NTOK 49
#define SCALE 0.17677669529663687f   // 1/sqrt(32)

// LDS blob layout (bytes).
#define XB_BASE   0            // bf16[49][256] swizzled  = 25,088
#define WB_BASE   25088        // 4 waves x 12,288        = 49,152
#define WB_SIZE   12288
#define QOFF      0            // bf16[64][32] swz        =  4,096
#define KOFF      4096         // bf16[64][32] swz        =  4,096
#define POFF      0            // bf16[64][64] swz, overlays q+k = 8,192
#define VTOFF     8192         // bf16[32][64] swz        =  4,096
#define TAB_BASE  74240        // bf16[1352]              =  2,704
#define SMEM_BYTES 76944       // 2 blocks/CU with >=7KB slack at any granule

// swizzle: byte ^= ((row&7)<<4); 16B granules move atomically.
#define XB_OFF(r,c)      (XB_BASE + ((((r) << 9) + ((c) << 1)) ^ (((r) & 7) << 4)))
#define QK_OFF(base,r,d) ((base) + ((((r) << 6) + ((d) << 1)) ^ (((r) & 7) << 4)))
#define P_OFF(base,r,c)  ((base) + ((((r) << 7) + ((c) << 1)) ^ (((r) & 7) << 4)))
#define VT_OFF(base,d,t) ((base) + ((((d) << 7) + ((t) << 1)) ^ (((d) & 7) << 4)))

__global__ __launch_bounds__(256) void swin_attn(
    const float* __restrict__ hidden, const float* __restrict__ mask_g,
    const float* __restrict__ bq_g, const float* __restrict__ bk_g,
    const float* __restrict__ bv_g, const float* __restrict__ table_g,
    const bf16* __restrict__ pkw, float* __restrict__ out)
{
    __shared__ __align__(16) unsigned char sm[SMEM_BYTES];

    const int tid  = threadIdx.x;
    const int b    = blockIdx.x;
    const int widx = b & 63;
    const float* hbase = hidden + (size_t)b * (NTOK * 256);
    const float* mbase = mask_g + widx * 2401;

    // ---- cooperative staging: x window fp32->bf16 (swizzled), tab -------
    for (int c4 = tid; c4 < 3136; c4 += 256) {      // 49*256/4 chunks
        int row = c4 >> 6;
        int col = (c4 & 63) << 2;                   // 8B-aligned dest
        f32x4 v = *(const f32x4*)(hbase + row * 256 + col);
        union { bf16 h[4]; unsigned long long u; } p;
        p.h[0] = (bf16)v[0]; p.h[1] = (bf16)v[1];
        p.h[2] = (bf16)v[2]; p.h[3] = (bf16)v[3];
        *(unsigned long long*)(sm + XB_OFF(row, col)) = p.u;
    }
    for (int i = tid; i < 1352; i += 256)
        *(bf16*)(sm + TAB_BASE + 2 * i) = (bf16)table_g[i];
    __syncthreads();   // the ONLY block-wide barrier

    const int wave = tid >> 6;
    const int L    = tid & 63;
    const int quad = L >> 4;
    const int cc   = L & 15;
    const int WB   = WB_BASE + wave * WB_SIZE;

    // ---- geometry: rel-pos linear coords per lane ----------------------
    int pr[16];
#pragma unroll
    for (int mt = 0; mt < 4; ++mt)
#pragma unroll
        for (int j = 0; j < 4; ++j) {
            int r = 16 * mt + 4 * quad + j;
            int rh = (r * 9363) >> 16;          // r / 7 for r < 64
            pr[mt * 4 + j] = 13 * rh + (r - 7 * rh);
        }
    int pc[4];
#pragma unroll
    for (int nt = 0; nt < 4; ++nt) {
        int c = 16 * nt + cc;
        int ch = (c * 9363) >> 16;
        pc[nt] = 13 * ch + (c - 7 * ch);
    }

    int arow[4];
#pragma unroll
    for (int mt = 0; mt < 4; ++mt) {
        int r = 16 * mt + cc;
        arow[mt] = (r > 48) ? 48 : r;           // clamped rows discarded later
    }

    // ---- per-head pipeline: wave w -> heads {w, w+4} -------------------
    for (int hp = 0; hp < 2; ++hp) {
        const int h = wave + 4 * hp;

        float bqv[2], bkv[2], bvv[2];
#pragma unroll
        for (int hf = 0; hf < 2; ++hf) {
            bqv[hf] = bq_g[h * 32 + hf * 16 + cc];
            bkv[hf] = bk_g[h * 32 + hf * 16 + cc];
            bvv[hf] = bv_g[h * 32 + hf * 16 + cc];
        }

        // ---- pass A: q,k projection (kk-outer; acc = 64 regs) ----------
        {
            f32x4 acc[2][2][4];
#pragma unroll
            for (int t = 0; t < 2; ++t)
#pragma unroll
                for (int hf = 0; hf < 2; ++hf)
#pragma unroll
                    for (int mt = 0; mt < 4; ++mt)
                        acc[t][hf][mt] = (f32x4){0.f, 0.f, 0.f, 0.f};
            const bf16* bpp[2][2];
#pragma unroll
            for (int t = 0; t < 2; ++t)
#pragma unroll
                for (int hf = 0; hf < 2; ++hf)
                    bpp[t][hf] = pkw + (((t * 16 + (h * 2 + hf)) * 8) << 9) + L * 8;
#pragma unroll 2
            for (int kk = 0; kk < 8; ++kk) {
                bf16x8 a[4];
#pragma unroll
                for (int mt = 0; mt < 4; ++mt)
                    a[mt] = *(const bf16x8*)(sm + XB_OFF(arow[mt], kk * 32 + quad * 8));
#pragma unroll
                for (int t = 0; t < 2; ++t)
#pragma unroll
                    for (int hf = 0; hf < 2; ++hf) {
                        bf16x8 bfv = *(const bf16x8*)(bpp[t][hf] + (kk << 9));
#pragma unroll
                        for (int mt = 0; mt < 4; ++mt)
                            acc[t][hf][mt] = mfma16(a[mt], bfv, acc[t][hf][mt]);
                    }
            }
#pragma unroll
            for (int t = 0; t < 2; ++t)
#pragma unroll
                for (int hf = 0; hf < 2; ++hf) {
                    const int d = hf * 16 + cc;
                    const int base = WB + (t == 0 ? QOFF : KOFF);
                    const float bias = (t == 0 ? bqv[hf] : bkv[hf]);
#pragma unroll
                    for (int mt = 0; mt < 4; ++mt)
#pragma unroll
                        for (int j = 0; j < 4; ++j) {
                            int row = 16 * mt + 4 * quad + j;
                            *(bf16*)(sm + QK_OFF(base, row, d)) =
                                (bf16)(acc[t][hf][mt][j] + bias);
                        }
                }
        }

        // ---- pass B: v projection (acc = 32 regs) ----------------------
        {
            f32x4 acc[2][4];
#pragma unroll
            for (int hf = 0; hf < 2; ++hf)
#pragma unroll
                for (int mt = 0; mt < 4; ++mt)
                    acc[hf][mt] = (f32x4){0.f, 0.f, 0.f, 0.f};
            const bf16* bpp[2];
#pragma unroll
            for (int hf = 0; hf < 2; ++hf)
                bpp[hf] = pkw + (((2 * 16 + (h * 2 + hf)) * 8) << 9) + L * 8;
#pragma unroll 2
            for (int kk = 0; kk < 8; ++kk) {
                bf16x8 a[4];
#pragma unroll
                for (int mt = 0; mt < 4; ++mt)
                    a[mt] = *(const bf16x8*)(sm + XB_OFF(arow[mt], kk * 32 + quad * 8));
#pragma unroll
                for (int hf = 0; hf < 2; ++hf) {
                    bf16x8 bfv = *(const bf16x8*)(bpp[hf] + (kk << 9));
#pragma unroll
                    for (int mt = 0; mt < 4; ++mt)
                        acc[hf][mt] = mfma16(a[mt], bfv, acc[hf][mt]);
                }
            }
#pragma unroll
            for (int hf = 0; hf < 2; ++hf) {
                const int d = hf * 16 + cc;
#pragma unroll
                for (int mt = 0; mt < 4; ++mt)
#pragma unroll
                    for (int j = 0; j < 4; ++j) {
                        int row = 16 * mt + 4 * quad + j;
                        *(bf16*)(sm + VT_OFF(WB + VTOFF, d, row)) =
                            (bf16)(acc[hf][mt][j] + bvv[hf]);
                    }
            }
        }

        // ---- preload fragments: q/k fully into regs (enables P overlay),
        //      v-frags reused across all mt ------------------------------
        bf16x8 aq[4], bkf[4], bvf[2][2];
#pragma unroll
        for (int mt = 0; mt < 4; ++mt)
            aq[mt] = *(const bf16x8*)(sm + QK_OFF(WB + QOFF, 16 * mt + cc, quad * 8));
#pragma unroll
        for (int nt = 0; nt < 4; ++nt)
            bkf[nt] = *(const bf16x8*)(sm + QK_OFF(WB + KOFF, 16 * nt + cc, quad * 8));
#pragma unroll
        for (int kk = 0; kk < 2; ++kk)
#pragma unroll
            for (int nt = 0; nt < 2; ++nt)
                bvf[kk][nt] = *(const bf16x8*)(sm + VT_OFF(WB + VTOFF, 16 * nt + cc,
                                                           kk * 32 + quad * 8));

        // ---- streamed per-16-row-block: scores -> softmax -> PV -> store
        float* op = out + (size_t)b * (NTOK * 256) + h * 32;
        const f32x4 z = (f32x4){0.f, 0.f, 0.f, 0.f};
#pragma unroll
        for (int mt = 0; mt < 4; ++mt) {
            f32x4 s[4];
#pragma unroll
            for (int nt = 0; nt < 4; ++nt)
                s[nt] = mfma16(aq[mt], bkf[nt], z);

            float linv[4];
#pragma unroll
            for (int j = 0; j < 4; ++j) {
                const int r = 16 * mt + 4 * quad + j;
                const float* mrow = mbase + r * 49;
                float vals[4];
#pragma unroll
                for (int nt = 0; nt < 4; ++nt) {
                    const int c = 16 * nt + cc;
                    float sc = s[nt][j] * SCALE;
                    if (r < 49 && c < 49) {
                        int idx = pr[mt * 4 + j] - pc[nt] + 84;
                        sc += (float)*(const bf16*)(sm + TAB_BASE + ((idx << 3) + h) * 2)
                            + mrow[c];                       // global fp32, L1-hot
                    } else {
                        sc = -1e30f;
                    }
                    vals[nt] = sc;
                }
                float mx = fmaxf(fmaxf(vals[0], vals[1]), fmaxf(vals[2], vals[3]));
                mx = fmaxf(mx, __shfl_xor(mx, 1));
                mx = fmaxf(mx, __shfl_xor(mx, 2));
                mx = fmaxf(mx, __shfl_xor(mx, 4));
                mx = fmaxf(mx, __shfl_xor(mx, 8));
                float sum = 0.f;
#pragma unroll
                for (int nt = 0; nt < 4; ++nt) {
                    float e = __expf(vals[nt] - mx);   // masked cols -> 0
                    sum += e;
                    *(bf16*)(sm + P_OFF(WB + POFF, r, 16 * nt + cc)) = (bf16)e;
                }
                sum += __shfl_xor(sum, 1);
                sum += __shfl_xor(sum, 2);
                sum += __shfl_xor(sum, 4);
                sum += __shfl_xor(sum, 8);
                linv[j] = 1.0f / sum;
            }

            // PV for this 16-row block (P rows 16mt..16mt+15 complete;
            // same-wave ds_write->ds_read ordered by compiler lgkmcnt)
            bf16x8 ap0 = *(const bf16x8*)(sm + P_OFF(WB + POFF, 16 * mt + cc, quad * 8));
            bf16x8 ap1 = *(const bf16x8*)(sm + P_OFF(WB + POFF, 16 * mt + cc, 32 + quad * 8));
            f32x4 o0 = z, o1 = z;
            o0 = mfma16(ap0, bvf[0][0], o0);
            o1 = mfma16(ap0, bvf[0][1], o1);
            o0 = mfma16(ap1, bvf[1][0], o0);
            o1 = mfma16(ap1, bvf[1][1], o1);

#pragma unroll
            for (int j = 0; j < 4; ++j) {
                const int r = 16 * mt + 4 * quad + j;
                if (r < 49) {
                    op[(size_t)r * 256 + cc]      = o0[j] * linv[j];
                    op[(size_t)r * 256 + 16 + cc] = o1[j] * linv[j];
                }
            }
        }
        // Fence the WAR hazard: next head's projection ds_writes must not
        // pass this head's P/vt ds_reads.
        asm volatile("s_waitcnt lgkmcnt(0)" ::: "memory");
    }
}

// --------------------------------------------------------------------------
extern "C" void kernel_launch(void* const* d_in, const int* in_sizes, int n_in,
                              void* d_out, int out_size, void* d_ws, size_t ws_size,
                              hipStream_t stream) {
    const float* hidden = (const float*)d_in[0];   // [4096,49,256]
    const float* mask   = (const float*)d_in[1];   // [64,49,49]
    const float* wq     = (const float*)d_in[2];   // [256,256]
    const float* bq     = (const float*)d_in[3];   // [256]
    const float* wk     = (const float*)d_in[4];
    const float* bk     = (const float*)d_in[5];
    const float* wv     = (const float*)d_in[6];
    const float* bv     = (const float*)d_in[7];
    const float* tab    = (const float*)d_in[8];   // [169,8]
    float* out = (float*)d_out;
    bf16* pkw = (bf16*)d_ws;                       // 393,216 B repacked weights

    repack_w<<<768, 256, 0, stream>>>(wq, wk, wv, pkw);
    swin_attn<<<4096, 256, 0, stream>>>(hidden, mask, bq, bk, bv, tab, pkw, out);
}